// Round 9
// baseline (1689.065 us; speedup 1.0000x reference)
//
#include <hip/hip_runtime.h>

typedef __attribute__((ext_vector_type(8))) short short8;
typedef __attribute__((ext_vector_type(4))) float f32x4;
typedef __attribute__((ext_vector_type(4))) unsigned int u32x4;

// ---------- helpers ----------
__device__ __forceinline__ unsigned short f2bu(float x) {
  unsigned int u = __float_as_uint(x);
  u += 0x7fffu + ((u >> 16) & 1u);
  return (unsigned short)(u >> 16);
}
__device__ __forceinline__ unsigned int pk2(float a, float b) {
  return (unsigned int)f2bu(a) | ((unsigned int)f2bu(b) << 16);
}
__device__ __forceinline__ void gload_lds16(const void* g, void* l) {
  __builtin_amdgcn_global_load_lds((const __attribute__((address_space(1))) unsigned int*)g,
                                   (__attribute__((address_space(3))) unsigned int*)l, 16, 0, 0);
}
__device__ __forceinline__ void store4_coh(void* p, unsigned int v) {
  asm volatile("global_store_dword %0, %1, off sc0 sc1" :: "v"(p), "v"(v) : "memory");
}

// ---------- cast & concat ----------
__global__ void cast_concat_kernel(const float* __restrict__ Mf,
                                   const float* __restrict__ DTf,
                                   const float* __restrict__ Df,
                                   unsigned short* __restrict__ ins) {
  size_t idx = (size_t)blockIdx.x * blockDim.x + threadIdx.x;
  size_t e0 = idx * 8;
  size_t m = e0 >> 10;
  int c = (int)(e0 & 1023);
  const float* src;
  if (c < 256)      src = Mf  + m * 256 + c;
  else if (c < 512) src = DTf + m * 256 + (c - 256);
  else              src = Df  + m * 512 + (c - 512);
  float4 f0 = reinterpret_cast<const float4*>(src)[0];
  float4 f1 = reinterpret_cast<const float4*>(src)[1];
  uint4 o;
  o.x = pk2(f0.x, f0.y); o.y = pk2(f0.z, f0.w);
  o.z = pk2(f1.x, f1.y); o.w = pk2(f1.z, f1.w);
  *reinterpret_cast<uint4*>(ins + e0) = o;
}

__global__ void cast_w_kernel(const float* __restrict__ in, unsigned short* __restrict__ out, int n8) {
  int idx = blockIdx.x * blockDim.x + threadIdx.x;
  if (idx >= n8) return;
  const float* src = in + (size_t)idx * 8;
  float4 f0 = reinterpret_cast<const float4*>(src)[0];
  float4 f1 = reinterpret_cast<const float4*>(src)[1];
  uint4 o;
  o.x = pk2(f0.x, f0.y); o.y = pk2(f0.z, f0.w);
  o.z = pk2(f1.x, f1.y); o.w = pk2(f1.z, f1.w);
  *reinterpret_cast<uint4*>(out + (size_t)idx * 8) = o;
}

// ---------- GEMM (m97 structure, unchanged) ----------
template <int RELU, typename TOUT>
__global__ __launch_bounds__(256) void gemm_bt_kernel(const unsigned short* __restrict__ A,
                                                      const unsigned short* __restrict__ Bt,
                                                      TOUT* __restrict__ C,
                                                      int M, int N, int K) {
  __shared__ unsigned short As[128 * 32];
  __shared__ unsigned short Bs[128 * 32];
  const int tid = threadIdx.x;
  const int l = tid & 63, w = tid >> 6;
  const int lr = l & 15, lg = l >> 4;
  const int wm = w >> 1, wn = w & 1;
  const int tiles_n = N >> 7;
  const int tm = blockIdx.x / tiles_n, tn = blockIdx.x % tiles_n;
  const int bm0 = tm << 7, bn0 = tn << 7;

  f32x4 acc[4][4] = {};

  for (int kt = 0; kt < K; kt += 32) {
#pragma unroll
    for (int i = 0; i < 2; ++i) {
      int ch = tid + (i << 8);
      int row = ch >> 2, cc = ch & 3;
      const unsigned short* ga = A + (size_t)(bm0 + row) * K + kt + cc * 8;
      const unsigned short* gb = Bt + (size_t)(bn0 + row) * K + kt + cc * 8;
      unsigned short* la = As + ((size_t)((i << 8) + (w << 6))) * 8;
      unsigned short* lb = Bs + ((size_t)((i << 8) + (w << 6))) * 8;
      gload_lds16(ga, la);
      gload_lds16(gb, lb);
    }
    __syncthreads();
    short8 af[4], bf[4];
#pragma unroll
    for (int mi = 0; mi < 4; ++mi)
      af[mi] = *reinterpret_cast<const short8*>(As + (wm * 64 + mi * 16 + lr) * 32 + lg * 8);
#pragma unroll
    for (int ni = 0; ni < 4; ++ni)
      bf[ni] = *reinterpret_cast<const short8*>(Bs + (wn * 64 + ni * 16 + lr) * 32 + lg * 8);
#pragma unroll
    for (int mi = 0; mi < 4; ++mi)
#pragma unroll
      for (int ni = 0; ni < 4; ++ni)
        acc[mi][ni] = __builtin_amdgcn_mfma_f32_16x16x32_bf16(af[mi], bf[ni], acc[mi][ni], 0, 0, 0);
    __syncthreads();
  }

#pragma unroll
  for (int mi = 0; mi < 4; ++mi)
#pragma unroll
    for (int ni = 0; ni < 4; ++ni)
#pragma unroll
      for (int r = 0; r < 4; ++r) {
        int row = bm0 + wm * 64 + mi * 16 + lg * 4 + r;
        int col = bn0 + wn * 64 + ni * 16 + lr;
        float v = acc[mi][ni][r];
        if (RELU) v = fmaxf(v, 0.f);
        if constexpr (sizeof(TOUT) == 2) {
          reinterpret_cast<unsigned short*>(C)[(size_t)row * N + col] = f2bu(v);
        } else {
          C[(size_t)row * N + col] = v;
        }
      }
}

// ---------- x0 init: tagged image of x_0 into buffer 0 ----------
// Layout per group (16KB): elem (i,j) -> byte (j>>5)*1024 + ((j>>3)&3)*256 + i*16 + (j&7)*2.
// Tag(t) = ((t>>1)&1)^1, forced into bit16 (LSB of high bf16) of every dword. tag(0)=1.
__global__ void xinit_tag(const float* __restrict__ x0, char* xexb) {
  int g = blockIdx.x;
  int tid = threadIdx.x;
  char* dst = xexb + g * 16384;
#pragma unroll
  for (int c = 0; c < 16; ++c) {
    int d = tid + (c << 8);                // dword 0..4095
    int ks = d >> 8, lgi = (d >> 6) & 3, i = (d >> 2) & 15, e = d & 3;
    int j = ks * 32 + lgi * 8 + e * 2;
    const float* s = x0 + (size_t)(g * 16 + i) * 512 + j;
    unsigned pv = pk2(s[0], s[1]);
    pv = (pv & 0xFFFEFFFFu) | (1u << 16);
    *reinterpret_cast<unsigned*>(dst + d * 4) = pv;
  }
}

// ---------- recurrence: tagged-data protocol, no flags/fences/barriers ----------
// 64 blocks = 16 groups x 4 quarters; W-quarter (128 cols) LDS-resident; 4 waves
// x 32 cols. Per step per wave: issue 16 coalesced sc0sc1 reg-loads of the full
// 16x512 A-tile (chunk ks at byte ks*1024 + lane*16 == MFMA A-frag layout),
// check per-dword tag bit, retry until fresh; 32 MFMA; publish tagged bf16.
#define ALOAD()                                                               \
  asm volatile(                                                               \
      "global_load_dwordx4 %0, %16, off sc0 sc1\n\t"                          \
      "global_load_dwordx4 %1, %16, off offset:1024 sc0 sc1\n\t"              \
      "global_load_dwordx4 %2, %16, off offset:2048 sc0 sc1\n\t"              \
      "global_load_dwordx4 %3, %16, off offset:3072 sc0 sc1\n\t"              \
      "global_load_dwordx4 %4, %17, off sc0 sc1\n\t"                          \
      "global_load_dwordx4 %5, %17, off offset:1024 sc0 sc1\n\t"              \
      "global_load_dwordx4 %6, %17, off offset:2048 sc0 sc1\n\t"              \
      "global_load_dwordx4 %7, %17, off offset:3072 sc0 sc1\n\t"              \
      "global_load_dwordx4 %8, %18, off sc0 sc1\n\t"                          \
      "global_load_dwordx4 %9, %18, off offset:1024 sc0 sc1\n\t"              \
      "global_load_dwordx4 %10, %18, off offset:2048 sc0 sc1\n\t"             \
      "global_load_dwordx4 %11, %18, off offset:3072 sc0 sc1\n\t"             \
      "global_load_dwordx4 %12, %19, off sc0 sc1\n\t"                         \
      "global_load_dwordx4 %13, %19, off offset:1024 sc0 sc1\n\t"             \
      "global_load_dwordx4 %14, %19, off offset:2048 sc0 sc1\n\t"             \
      "global_load_dwordx4 %15, %19, off offset:3072 sc0 sc1\n\t"             \
      : "=&v"(c0), "=&v"(c1), "=&v"(c2), "=&v"(c3), "=&v"(c4), "=&v"(c5),     \
        "=&v"(c6), "=&v"(c7), "=&v"(c8), "=&v"(c9), "=&v"(c10), "=&v"(c11),   \
        "=&v"(c12), "=&v"(c13), "=&v"(c14), "=&v"(c15)                        \
      : "v"(ab0), "v"(ab1), "v"(ab2), "v"(ab3)                                \
      : "memory")

#define CHK(C) bad |= (((C).x ^ tgm) | ((C).y ^ tgm) | ((C).z ^ tgm) | ((C).w ^ tgm)) & 0x10000u

#define MF(C, KK)                                                             \
  {                                                                           \
    short8 w0f = *reinterpret_cast<const short8*>(wb0 + (((KK)*64 + lg16) ^ sww)); \
    short8 w1f = *reinterpret_cast<const short8*>(wb1 + (((KK)*64 + lg16) ^ sww)); \
    short8 af = __builtin_bit_cast(short8, C);                                \
    acc0 = __builtin_amdgcn_mfma_f32_16x16x32_bf16(af, w0f, acc0, 0, 0, 0);   \
    acc1 = __builtin_amdgcn_mfma_f32_16x16x32_bf16(af, w1f, acc1, 0, 0, 0);   \
  }

__global__ __launch_bounds__(256)
void recurrence_tag(const float* __restrict__ Whh1,
                    const float* __restrict__ G,
                    char* xexb,              // [2][16 groups][16KB]
                    float* __restrict__ X, float* __restrict__ Y) {
  __shared__ char smem[131072];   // W-quarter, swizzled
  const int tid = threadIdx.x;
  const int l = tid & 63, wv = tid >> 6;
  const int lr = l & 15, lg = l >> 4;
  const int g = blockIdx.x >> 2, q = blockIdx.x & 3;
  const int r0 = g << 4;
  char* Wl = smem;

  // ---- one-time: swizzled W-quarter image (rows 128q..128q+128) ----
  {
    int j = tid >> 1;
    int kc0 = (tid & 1) << 8;
    const float* wr = Whh1 + (size_t)(128 * q + j) * 512 + kc0;
    int sw = (j & 7) << 4;
    for (int kk = 0; kk < 256; kk += 8) {
      float4 f0 = reinterpret_cast<const float4*>(wr + kk)[0];
      float4 f1 = reinterpret_cast<const float4*>(wr + kk)[1];
      uint4 o;
      o.x = pk2(f0.x, f0.y); o.y = pk2(f0.z, f0.w);
      o.z = pk2(f1.x, f1.y); o.w = pk2(f1.z, f1.w);
      *reinterpret_cast<uint4*>(Wl + j * 1024 + ((2 * (kc0 + kk)) ^ sw)) = o;
    }
  }
  __syncthreads();

  const int jl0 = wv * 32 + lr, jl1 = jl0 + 16;
  const int j0 = q * 128 + jl0, j1 = q * 128 + jl1;
  const char* wb0 = Wl + jl0 * 1024;
  const char* wb1 = Wl + jl1 * 1024;
  const int sww = (jl0 & 7) << 4;      // (jl1&7) identical
  const int lg16 = lg << 4;

  for (int t = 0; t < 256; ++t) {
    // ---- poll-load A-tile (fresh-or-retry), G loads ride under the RT ----
    const char* xrb = xexb + (((t & 1) * 16 + g) * 16384) + l * 16;
    const char* ab0 = xrb;
    const char* ab1 = xrb + 4096;
    const char* ab2 = xrb + 8192;
    const char* ab3 = xrb + 12288;
    u32x4 c0, c1, c2, c3, c4, c5, c6, c7, c8, c9, c10, c11, c12, c13, c14, c15;
    ALOAD();
    float gv0, gv1, gv2, gv3, gv4, gv5, gv6, gv7;
    {
      const float* Gt = G + ((size_t)t * 256 + r0 + lg * 4) * 512;
      gv0 = Gt[j0]; gv1 = Gt[512 + j0]; gv2 = Gt[1024 + j0]; gv3 = Gt[1536 + j0];
      gv4 = Gt[j1]; gv5 = Gt[512 + j1]; gv6 = Gt[1024 + j1]; gv7 = Gt[1536 + j1];
    }
    asm volatile("s_waitcnt vmcnt(8)" ::: "memory");   // 16 A-loads done; G may fly
    __builtin_amdgcn_sched_barrier(0);
    const unsigned tgm = (unsigned)((((t >> 1) & 1) ^ 1) << 16);
    for (;;) {
      unsigned bad = 0;
      CHK(c0); CHK(c1); CHK(c2); CHK(c3); CHK(c4); CHK(c5); CHK(c6); CHK(c7);
      CHK(c8); CHK(c9); CHK(c10); CHK(c11); CHK(c12); CHK(c13); CHK(c14); CHK(c15);
      if (__all(bad == 0)) break;
      ALOAD();
      asm volatile("s_waitcnt vmcnt(0)" ::: "memory");
      __builtin_amdgcn_sched_barrier(0);
    }

    // ---- 32 MFMA (2 chains), W from LDS ----
    f32x4 acc0 = {}, acc1 = {};
    MF(c0, 0)  MF(c1, 1)  MF(c2, 2)  MF(c3, 3)
    MF(c4, 4)  MF(c5, 5)  MF(c6, 6)  MF(c7, 7)
    MF(c8, 8)  MF(c9, 9)  MF(c10, 10) MF(c11, 11)
    MF(c12, 12) MF(c13, 13) MF(c14, 14) MF(c15, 15)

    // ---- epilogue ----
    float v0r0 = fmaxf(gv0 + acc0[0], 0.f), v0r1 = fmaxf(gv1 + acc0[1], 0.f);
    float v0r2 = fmaxf(gv2 + acc0[2], 0.f), v0r3 = fmaxf(gv3 + acc0[3], 0.f);
    float v1r0 = fmaxf(gv4 + acc1[0], 0.f), v1r1 = fmaxf(gv5 + acc1[1], 0.f);
    float v1r2 = fmaxf(gv6 + acc1[2], 0.f), v1r3 = fmaxf(gv7 + acc1[3], 0.f);

    {
      float* Xt = X + ((size_t)t * 256 + r0 + lg * 4) * 512;
      Xt[j0] = v0r0; Xt[512 + j0] = v0r1; Xt[1024 + j0] = v0r2; Xt[1536 + j0] = v0r3;
      Xt[j1] = v1r0; Xt[512 + j1] = v1r1; Xt[1024 + j1] = v1r2; Xt[1536 + j1] = v1r3;
    }
    if (t < 255) {
      const unsigned tgn16 = (unsigned)(((((t + 1) >> 1) & 1) ^ 1) << 16);
      char* pb = xexb + ((((t + 1) & 1) * 16 + g) * 16384);
      float va[8] = {v0r0, v0r1, v0r2, v0r3, v1r0, v1r1, v1r2, v1r3};
#pragma unroll
      for (int jt = 0; jt < 2; ++jt) {
        int jg = (jt == 0) ? j0 : j1;
        int base = (jg >> 5) * 1024 + ((jg >> 3) & 3) * 256 + (jg & 7) * 2;
#pragma unroll
        for (int r = 0; r < 4; ++r) {
          float v = va[jt * 4 + r];
          float vn = __shfl_xor(v, 1);
          if (!(lr & 1)) {
            int i = lg * 4 + r;
            unsigned pv = (pk2(v, vn) & 0xFFFEFFFFu) | tgn16;
            store4_coh(pb + base + i * 16, pv);
          }
        }
      }
    }
    if (q == 3 && wv == 3 && lr == 15) {
      Y[t * 256 + r0 + lg * 4 + 0] = v1r0;
      Y[t * 256 + r0 + lg * 4 + 1] = v1r1;
      Y[t * 256 + r0 + lg * 4 + 2] = v1r2;
      Y[t * 256 + r0 + lg * 4 + 3] = v1r3;
    }
  }
}

// ---------- launch ----------
extern "C" void kernel_launch(void* const* d_in, const int* in_sizes, int n_in,
                              void* d_out, int out_size, void* d_ws, size_t ws_size,
                              hipStream_t stream) {
  const float* x0   = (const float*)d_in[0];
  const float* Mf   = (const float*)d_in[1];
  const float* DTf  = (const float*)d_in[2];
  const float* Df   = (const float*)d_in[3];
  const float* Wih0 = (const float*)d_in[4];
  const float* Wih1 = (const float*)d_in[6];
  const float* Whh1 = (const float*)d_in[7];

  char* ws = (char*)d_ws;
  unsigned short* ins = (unsigned short*)(ws);
  unsigned short* H   = (unsigned short*)(ws + 134217728ULL);
  unsigned short* w0b = (unsigned short*)(ws + 268435456ULL);
  unsigned short* w1b = (unsigned short*)(ws + 270532608ULL);
  char* xex           = ws + 271581184ULL;                     // 512KB: [2][16][16KB]
  float* G = (float*)(ws);   // aliases ins (dead after GEMM1)

  cast_concat_kernel<<<32768, 256, 0, stream>>>(Mf, DTf, Df, ins);
  cast_w_kernel<<<512, 256, 0, stream>>>(Wih0, w0b, 131072);
  cast_w_kernel<<<256, 256, 0, stream>>>(Wih1, w1b, 65536);
  xinit_tag<<<16, 256, 0, stream>>>(x0, xex);

  gemm_bt_kernel<1, unsigned short><<<(65536 / 128) * (1024 / 128), 256, 0, stream>>>(
      ins, w0b, H, 65536, 1024, 1024);
  gemm_bt_kernel<0, float><<<(65536 / 128) * (512 / 128), 256, 0, stream>>>(
      H, w1b, G, 65536, 512, 1024);

  float* X = (float*)d_out;
  float* Y = X + 33554432;
  recurrence_tag<<<64, 256, 0, stream>>>(Whh1, G, xex, X, Y);
}

// Round 11
// 1170.879 us; speedup vs baseline: 1.4426x; 1.4426x over previous
//
#include <hip/hip_runtime.h>

typedef __attribute__((ext_vector_type(8))) short short8;
typedef __attribute__((ext_vector_type(4))) float f32x4;
typedef __attribute__((ext_vector_type(4))) unsigned int u32x4;

// ---------- helpers ----------
__device__ __forceinline__ unsigned short f2bu(float x) {
  unsigned int u = __float_as_uint(x);
  u += 0x7fffu + ((u >> 16) & 1u);
  return (unsigned short)(u >> 16);
}
__device__ __forceinline__ unsigned int pk2(float a, float b) {
  return (unsigned int)f2bu(a) | ((unsigned int)f2bu(b) << 16);
}
__device__ __forceinline__ void gload_lds16(const void* g, void* l) {
  __builtin_amdgcn_global_load_lds((const __attribute__((address_space(1))) unsigned int*)g,
                                   (__attribute__((address_space(3))) unsigned int*)l, 16, 0, 0);
}
// coherent DMA (sc0|sc1): reads from the coherence point — proven r8/r9
__device__ __forceinline__ void gload_lds16_coh(const void* g, void* l) {
  __builtin_amdgcn_global_load_lds((const __attribute__((address_space(1))) unsigned int*)g,
                                   (__attribute__((address_space(3))) unsigned int*)l, 16, 0, 17);
}
__device__ __forceinline__ void store16_coh(void* p, u32x4 v) {
  asm volatile("global_store_dwordx4 %0, %1, off sc0 sc1" :: "v"(p), "v"(v) : "memory");
}

// ---------- cast & concat ----------
__global__ void cast_concat_kernel(const float* __restrict__ Mf,
                                   const float* __restrict__ DTf,
                                   const float* __restrict__ Df,
                                   unsigned short* __restrict__ ins) {
  size_t idx = (size_t)blockIdx.x * blockDim.x + threadIdx.x;
  size_t e0 = idx * 8;
  size_t m = e0 >> 10;
  int c = (int)(e0 & 1023);
  const float* src;
  if (c < 256)      src = Mf  + m * 256 + c;
  else if (c < 512) src = DTf + m * 256 + (c - 256);
  else              src = Df  + m * 512 + (c - 512);
  float4 f0 = reinterpret_cast<const float4*>(src)[0];
  float4 f1 = reinterpret_cast<const float4*>(src)[1];
  uint4 o;
  o.x = pk2(f0.x, f0.y); o.y = pk2(f0.z, f0.w);
  o.z = pk2(f1.x, f1.y); o.w = pk2(f1.z, f1.w);
  *reinterpret_cast<uint4*>(ins + e0) = o;
}

__global__ void cast_w_kernel(const float* __restrict__ in, unsigned short* __restrict__ out, int n8) {
  int idx = blockIdx.x * blockDim.x + threadIdx.x;
  if (idx >= n8) return;
  const float* src = in + (size_t)idx * 8;
  float4 f0 = reinterpret_cast<const float4*>(src)[0];
  float4 f1 = reinterpret_cast<const float4*>(src)[1];
  uint4 o;
  o.x = pk2(f0.x, f0.y); o.y = pk2(f0.z, f0.w);
  o.z = pk2(f1.x, f1.y); o.w = pk2(f1.z, f1.w);
  *reinterpret_cast<uint4*>(out + (size_t)idx * 8) = o;
}

// ---------- GEMM (m97 structure, unchanged) ----------
template <int RELU, typename TOUT>
__global__ __launch_bounds__(256) void gemm_bt_kernel(const unsigned short* __restrict__ A,
                                                      const unsigned short* __restrict__ Bt,
                                                      TOUT* __restrict__ C,
                                                      int M, int N, int K) {
  __shared__ unsigned short As[128 * 32];
  __shared__ unsigned short Bs[128 * 32];
  const int tid = threadIdx.x;
  const int l = tid & 63, w = tid >> 6;
  const int lr = l & 15, lg = l >> 4;
  const int wm = w >> 1, wn = w & 1;
  const int tiles_n = N >> 7;
  const int tm = blockIdx.x / tiles_n, tn = blockIdx.x % tiles_n;
  const int bm0 = tm << 7, bn0 = tn << 7;

  f32x4 acc[4][4] = {};

  for (int kt = 0; kt < K; kt += 32) {
#pragma unroll
    for (int i = 0; i < 2; ++i) {
      int ch = tid + (i << 8);
      int row = ch >> 2, cc = ch & 3;
      const unsigned short* ga = A + (size_t)(bm0 + row) * K + kt + cc * 8;
      const unsigned short* gb = Bt + (size_t)(bn0 + row) * K + kt + cc * 8;
      unsigned short* la = As + ((size_t)((i << 8) + (w << 6))) * 8;
      unsigned short* lb = Bs + ((size_t)((i << 8) + (w << 6))) * 8;
      gload_lds16(ga, la);
      gload_lds16(gb, lb);
    }
    __syncthreads();
    short8 af[4], bf[4];
#pragma unroll
    for (int mi = 0; mi < 4; ++mi)
      af[mi] = *reinterpret_cast<const short8*>(As + (wm * 64 + mi * 16 + lr) * 32 + lg * 8);
#pragma unroll
    for (int ni = 0; ni < 4; ++ni)
      bf[ni] = *reinterpret_cast<const short8*>(Bs + (wn * 64 + ni * 16 + lr) * 32 + lg * 8);
#pragma unroll
    for (int mi = 0; mi < 4; ++mi)
#pragma unroll
      for (int ni = 0; ni < 4; ++ni)
        acc[mi][ni] = __builtin_amdgcn_mfma_f32_16x16x32_bf16(af[mi], bf[ni], acc[mi][ni], 0, 0, 0);
    __syncthreads();
  }

#pragma unroll
  for (int mi = 0; mi < 4; ++mi)
#pragma unroll
    for (int ni = 0; ni < 4; ++ni)
#pragma unroll
      for (int r = 0; r < 4; ++r) {
        int row = bm0 + wm * 64 + mi * 16 + lg * 4 + r;
        int col = bn0 + wn * 64 + ni * 16 + lr;
        float v = acc[mi][ni][r];
        if (RELU) v = fmaxf(v, 0.f);
        if constexpr (sizeof(TOUT) == 2) {
          reinterpret_cast<unsigned short*>(C)[(size_t)row * N + col] = f2bu(v);
        } else {
          C[(size_t)row * N + col] = v;
        }
      }
}

// ---------- xex scrub: invalid tags (all-zero) at coherence point, each launch ----------
__global__ void xscrub_kernel(char* xexb) {
  size_t idx = (size_t)blockIdx.x * blockDim.x + threadIdx.x;
  u32x4 z = {0, 0, 0, 0};
  store16_coh(xexb + idx * 16, z);
}

// ---------- recurrence: flag-free tag-verified exchange ----------
// 64 blocks = 16 groups x 4 quarters (r7 mapping). W-quarter LDS-resident.
// x image per group/parity: [4 slices][16 rows][256B], byte = q*4096 + i*256
// + ((2*jc)^((i&7)<<4)). Tag: bit16 of dword at pair-pos p equals s^(p&1),
// s=(t>>1)&1. Producer publishes tagged slice sc0sc1 fire-and-forget; consumer
// speculatively DMAs (aux17), verifies tags on the frags it reads anyway,
// retries on staleness (epoch-word verdict, cap 64). No flags/fences/acks.
__global__ __launch_bounds__(256)
void recurrence_tf(const float* __restrict__ Whh1,
                   const float* __restrict__ x0f,
                   const float* __restrict__ G,
                   char* xexb,              // [2][16 groups][16KB]
                   float* __restrict__ X, float* __restrict__ Y) {
  __shared__ char smem[163840];   // [0,128K) W; [128K,144K) xls0; [144K,160K) xls1
  const int tid = threadIdx.x;
  const int l = tid & 63, wv = tid >> 6;
  const int lr = l & 15, lg = l >> 4;
  const int bid = blockIdx.x;
  const int g = ((bid & 7) << 1) | ((bid >> 3) & 1);
  const int q = bid >> 4;
  const int r0 = g << 4;
  const int jbw = wv << 5;
  char* Wl = smem;
  char* xls0 = smem + 131072;
  char* xls1 = smem + 147456;

  // ---- one-time: swizzled W-quarter image (rows 128q..128q+128) ----
  {
    int j = tid >> 1;
    int kc0 = (tid & 1) << 8;
    const float* wr = Whh1 + (size_t)(128 * q + j) * 512 + kc0;
    int sw = (j & 7) << 4;
    for (int kk = 0; kk < 256; kk += 8) {
      float4 f0 = reinterpret_cast<const float4*>(wr + kk)[0];
      float4 f1 = reinterpret_cast<const float4*>(wr + kk)[1];
      uint4 o;
      o.x = pk2(f0.x, f0.y); o.y = pk2(f0.z, f0.w);
      o.z = pk2(f1.x, f1.y); o.w = pk2(f1.z, f1.w);
      *reinterpret_cast<uint4*>(Wl + j * 1024 + ((2 * (kc0 + kk)) ^ sw)) = o;
    }
  }
  // ---- one-time: full x_0 image into xls0 (untagged; never exchanged) ----
#pragma unroll
  for (int c = 0; c < 4; ++c) {
    int id = tid + (c << 8);
    int row = id >> 6;
    int kc = (id & 63) << 3;
    int qq = kc >> 7, kp = kc & 127;
    const float* src = x0f + (size_t)(r0 + row) * 512 + kc;
    float4 f0 = reinterpret_cast<const float4*>(src)[0];
    float4 f1 = reinterpret_cast<const float4*>(src)[1];
    uint4 o;
    o.x = pk2(f0.x, f0.y); o.y = pk2(f0.z, f0.w);
    o.z = pk2(f1.x, f1.y); o.w = pk2(f1.z, f1.w);
    *reinterpret_cast<uint4*>(xls0 + qq * 4096 + row * 256 +
                              ((2 * kp) ^ ((row & 7) << 4))) = o;
  }

  // G for t=0
  float gcur[8], gnxt[8];
#pragma unroll
  for (int jt = 0; jt < 2; ++jt)
#pragma unroll
    for (int r = 0; r < 4; ++r)
      gcur[jt * 4 + r] = G[((size_t)r0 + lg * 4 + r) * 512 + q * 128 + jbw + jt * 16 + lr];
  __syncthreads();

  const int swzR = (lr & 7) << 4;
  int rq[3];
  {
    int n = 0;
    for (int qq = 0; qq < 4; ++qq)
      if (qq != q) rq[n++] = qq;
  }
  float vsave[8];
  short8 arr[12];
  int ep = 1;   // monotone epoch for verdict word (block-uniform)

  for (int t = 0; t < 256; ++t) {
    char* xc = (t & 1) ? xls1 : xls0;
    const unsigned sh = (unsigned)(((t >> 1) & 1) << 16);
    const u32x4 e = {sh, sh ^ 0x10000u, sh, sh ^ 0x10000u};

    // ---- phase 1: speculative DMA of remote slices (aux17) ----
    if (t) {
      const char* xsb = xexb + (((t & 1) * 16 + g) * 16384);
#pragma unroll
      for (int m = 0; m < 3; ++m)
        gload_lds16_coh(xsb + rq[m] * 4096 + wv * 1024 + (size_t)l * 16,
                        xc + rq[m] * 4096 + wv * 1024);
    }

    // ---- phase A: own-quarter MFMAs (local LDS, hides DMA RT) ----
    f32x4 acc[2] = {};
    {
      short8 ao[4];
#pragma unroll
      for (int kp = 0; kp < 4; ++kp)
        ao[kp] = *reinterpret_cast<const short8*>(
            xc + q * 4096 + lr * 256 + ((kp * 64 + lg * 16) ^ swzR));
#pragma unroll
      for (int jt = 0; jt < 2; ++jt) {
        int jl = jbw + jt * 16 + lr;
        const char* wb = Wl + jl * 1024;
        int swj = (jl & 7) << 4;
#pragma unroll
        for (int kp = 0; kp < 4; ++kp) {
          short8 wf = *reinterpret_cast<const short8*>(
              wb + (((q * 4 + kp) * 64 + lg * 16) ^ swj));
          acc[jt] = __builtin_amdgcn_mfma_f32_16x16x32_bf16(ao[kp], wf, acc[jt], 0, 0, 0);
        }
      }
    }

    // ---- phase B: land DMA, read + tag-verify remote frags (retry loop) ----
    unsigned mybad = 0;
#define READCHECK()                                                           \
  {                                                                           \
    mybad = 0;                                                                \
    _Pragma("unroll") for (int m = 0; m < 3; ++m) {                           \
      int qq = rq[m];                                                         \
      _Pragma("unroll") for (int kp = 0; kp < 4; ++kp) {                      \
        short8 f = *reinterpret_cast<const short8*>(                          \
            xc + qq * 4096 + lr * 256 + ((kp * 64 + lg * 16) ^ swzR));        \
        arr[m * 4 + kp] = f;                                                  \
        u32x4 d = __builtin_bit_cast(u32x4, f);                               \
        u32x4 xr = (d ^ e) & 0x10000u;                                        \
        mybad |= xr.x | xr.y | xr.z | xr.w;                                   \
      }                                                                       \
    }                                                                         \
  }
    if (t) {
      asm volatile("s_waitcnt vmcnt(0)" ::: "memory");
      __builtin_amdgcn_sched_barrier(0);
      __syncthreads();
      READCHECK();
      int* badw = (int*)(xc + q * 4096);   // aliases own-slice dword0 (safe: phase-A reads done)
      for (int it = 0; it < 64; ++it) {
        if (__any(mybad != 0)) { if (l == 0) *badw = ep; }
        __syncthreads();
        bool bad = (*badw == ep);
        ++ep;
        if (!bad) break;
        const char* xsb = xexb + (((t & 1) * 16 + g) * 16384);
#pragma unroll
        for (int m = 0; m < 3; ++m)
          gload_lds16_coh(xsb + rq[m] * 4096 + wv * 1024 + (size_t)l * 16,
                          xc + rq[m] * 4096 + wv * 1024);
        asm volatile("s_waitcnt vmcnt(0)" ::: "memory");
        __builtin_amdgcn_sched_barrier(0);
        __syncthreads();
        READCHECK();
      }
    } else {
      READCHECK();   // all-local x0, no verification needed
    }
#undef READCHECK

    // ---- phase 6: deferred X/Y for t-1, G prefetch for t+1 (hide under MFMA) ----
    if (t) {
      float* Xp = X + ((size_t)(t - 1) * 256 + r0) * 512 + q * 128;
#pragma unroll
      for (int jt = 0; jt < 2; ++jt)
#pragma unroll
        for (int r = 0; r < 4; ++r)
          Xp[(size_t)(lg * 4 + r) * 512 + jbw + jt * 16 + lr] = vsave[jt * 4 + r];
      if (q == 3 && wv == 3 && lr == 15)
#pragma unroll
        for (int r = 0; r < 4; ++r)
          Y[(t - 1) * 256 + r0 + lg * 4 + r] = vsave[4 + r];
    }
    {
      int tn = (t < 255) ? t + 1 : t;
      const float* Gn = G + ((size_t)tn * 256 + r0) * 512 + q * 128;
#pragma unroll
      for (int jt = 0; jt < 2; ++jt)
#pragma unroll
        for (int r = 0; r < 4; ++r)
          gnxt[jt * 4 + r] = Gn[(size_t)(lg * 4 + r) * 512 + jbw + jt * 16 + lr];
    }

    // ---- phase C: remote-quarter MFMAs from verified frags ----
#pragma unroll
    for (int m = 0; m < 3; ++m) {
      int qq = rq[m];
#pragma unroll
      for (int jt = 0; jt < 2; ++jt) {
        int jl = jbw + jt * 16 + lr;
        const char* wb = Wl + jl * 1024;
        int swj = (jl & 7) << 4;
#pragma unroll
        for (int kp = 0; kp < 4; ++kp) {
          short8 wf = *reinterpret_cast<const short8*>(
              wb + (((qq * 4 + kp) * 64 + lg * 16) ^ swj));
          acc[jt] = __builtin_amdgcn_mfma_f32_16x16x32_bf16(arr[m * 4 + kp], wf, acc[jt], 0, 0, 0);
        }
      }
    }

    // ---- phase D: epilogue ----
#pragma unroll
    for (int jt = 0; jt < 2; ++jt)
#pragma unroll
      for (int r = 0; r < 4; ++r)
        vsave[jt * 4 + r] = fmaxf(gcur[jt * 4 + r] + acc[jt][r], 0.f);
#pragma unroll
    for (int ee = 0; ee < 8; ++ee) gcur[ee] = gnxt[ee];

    if (t < 255) {
      char* xn = (t & 1) ? xls0 : xls1;
      const unsigned snext = (unsigned)(((t + 1) >> 1) & 1);
#pragma unroll
      for (int jt = 0; jt < 2; ++jt)
#pragma unroll
        for (int r = 0; r < 4; ++r) {
          float v = vsave[jt * 4 + r];
          float vn = __shfl_xor(v, 1);
          if (!(lr & 1)) {
            int i = lg * 4 + r;
            int jc = jbw + jt * 16 + lr;
            unsigned pv = pk2(v, vn);
            pv = (pv & ~0x10000u) | ((snext ^ (unsigned)((jc >> 1) & 1)) << 16);
            *reinterpret_cast<unsigned int*>(
                xn + q * 4096 + i * 256 + ((2 * jc) ^ ((i & 7) << 4))) = pv;
          }
        }
      // publish own slice: coalesced, fire-and-forget (tag IS the flag)
      __syncthreads();
      char* xd = xexb + ((((t + 1) & 1) * 16 + g) * 16384) + q * 4096;
      u32x4 val = *reinterpret_cast<const u32x4*>(xn + q * 4096 + tid * 16);
      store16_coh(xd + tid * 16, val);
    }
  }

  // final X/Y for t=255
  {
    float* Xp = X + ((size_t)255 * 256 + r0) * 512 + q * 128;
#pragma unroll
    for (int jt = 0; jt < 2; ++jt)
#pragma unroll
      for (int r = 0; r < 4; ++r)
        Xp[(size_t)(lg * 4 + r) * 512 + jbw + jt * 16 + lr] = vsave[jt * 4 + r];
    if (q == 3 && wv == 3 && lr == 15)
#pragma unroll
      for (int r = 0; r < 4; ++r)
        Y[255 * 256 + r0 + lg * 4 + r] = vsave[4 + r];
  }
}

// ---------- launch ----------
extern "C" void kernel_launch(void* const* d_in, const int* in_sizes, int n_in,
                              void* d_out, int out_size, void* d_ws, size_t ws_size,
                              hipStream_t stream) {
  const float* x0   = (const float*)d_in[0];
  const float* Mf   = (const float*)d_in[1];
  const float* DTf  = (const float*)d_in[2];
  const float* Df   = (const float*)d_in[3];
  const float* Wih0 = (const float*)d_in[4];
  const float* Wih1 = (const float*)d_in[6];
  const float* Whh1 = (const float*)d_in[7];

  char* ws = (char*)d_ws;
  unsigned short* ins = (unsigned short*)(ws);
  unsigned short* H   = (unsigned short*)(ws + 134217728ULL);
  unsigned short* w0b = (unsigned short*)(ws + 268435456ULL);
  unsigned short* w1b = (unsigned short*)(ws + 270532608ULL);
  char* xex           = ws + 271581184ULL;                     // 512KB: [2][16][16KB]
  float* G = (float*)(ws);   // aliases ins (dead after GEMM1)

  xscrub_kernel<<<128, 256, 0, stream>>>(xex);   // invalid tags each launch (replay-safe)
  cast_concat_kernel<<<32768, 256, 0, stream>>>(Mf, DTf, Df, ins);
  cast_w_kernel<<<512, 256, 0, stream>>>(Wih0, w0b, 131072);
  cast_w_kernel<<<256, 256, 0, stream>>>(Wih1, w1b, 65536);

  gemm_bt_kernel<1, unsigned short><<<(65536 / 128) * (1024 / 128), 256, 0, stream>>>(
      ins, w0b, H, 65536, 1024, 1024);
  gemm_bt_kernel<0, float><<<(65536 / 128) * (512 / 128), 256, 0, stream>>>(
      H, w1b, G, 65536, 512, 1024);

  float* X = (float*)d_out;
  float* Y = X + 33554432;
  recurrence_tf<<<64, 256, 0, stream>>>(Whh1, x0, G, xex, X, Y);
}

// Round 12
// 1082.733 us; speedup vs baseline: 1.5600x; 1.0814x over previous
//
#include <hip/hip_runtime.h>

typedef __attribute__((ext_vector_type(8))) short short8;
typedef __attribute__((ext_vector_type(4))) float f32x4;
typedef __attribute__((ext_vector_type(4))) unsigned int u32x4;

// ---------- helpers ----------
__device__ __forceinline__ unsigned short f2bu(float x) {
  unsigned int u = __float_as_uint(x);
  u += 0x7fffu + ((u >> 16) & 1u);
  return (unsigned short)(u >> 16);
}
__device__ __forceinline__ unsigned int pk2(float a, float b) {
  return (unsigned int)f2bu(a) | ((unsigned int)f2bu(b) << 16);
}
__device__ __forceinline__ void gload_lds16(const void* g, void* l) {
  __builtin_amdgcn_global_load_lds((const __attribute__((address_space(1))) unsigned int*)g,
                                   (__attribute__((address_space(3))) unsigned int*)l, 16, 0, 0);
}
// coherent DMA (sc0|sc1): reads from the coherence point — proven r8/r9/r11
__device__ __forceinline__ void gload_lds16_coh(const void* g, void* l) {
  __builtin_amdgcn_global_load_lds((const __attribute__((address_space(1))) unsigned int*)g,
                                   (__attribute__((address_space(3))) unsigned int*)l, 16, 0, 17);
}
__device__ __forceinline__ void store16_coh(void* p, u32x4 v) {
  asm volatile("global_store_dwordx4 %0, %1, off sc0 sc1" :: "v"(p), "v"(v) : "memory");
}

// ---------- cast & concat ----------
__global__ void cast_concat_kernel(const float* __restrict__ Mf,
                                   const float* __restrict__ DTf,
                                   const float* __restrict__ Df,
                                   unsigned short* __restrict__ ins) {
  size_t idx = (size_t)blockIdx.x * blockDim.x + threadIdx.x;
  size_t e0 = idx * 8;
  size_t m = e0 >> 10;
  int c = (int)(e0 & 1023);
  const float* src;
  if (c < 256)      src = Mf  + m * 256 + c;
  else if (c < 512) src = DTf + m * 256 + (c - 256);
  else              src = Df  + m * 512 + (c - 512);
  float4 f0 = reinterpret_cast<const float4*>(src)[0];
  float4 f1 = reinterpret_cast<const float4*>(src)[1];
  uint4 o;
  o.x = pk2(f0.x, f0.y); o.y = pk2(f0.z, f0.w);
  o.z = pk2(f1.x, f1.y); o.w = pk2(f1.z, f1.w);
  *reinterpret_cast<uint4*>(ins + e0) = o;
}

__global__ void cast_w_kernel(const float* __restrict__ in, unsigned short* __restrict__ out, int n8) {
  int idx = blockIdx.x * blockDim.x + threadIdx.x;
  if (idx >= n8) return;
  const float* src = in + (size_t)idx * 8;
  float4 f0 = reinterpret_cast<const float4*>(src)[0];
  float4 f1 = reinterpret_cast<const float4*>(src)[1];
  uint4 o;
  o.x = pk2(f0.x, f0.y); o.y = pk2(f0.z, f0.w);
  o.z = pk2(f1.x, f1.y); o.w = pk2(f1.z, f1.w);
  *reinterpret_cast<uint4*>(out + (size_t)idx * 8) = o;
}

// ---------- GEMM (m97 structure, unchanged) ----------
template <int RELU, typename TOUT>
__global__ __launch_bounds__(256) void gemm_bt_kernel(const unsigned short* __restrict__ A,
                                                      const unsigned short* __restrict__ Bt,
                                                      TOUT* __restrict__ C,
                                                      int M, int N, int K) {
  __shared__ unsigned short As[128 * 32];
  __shared__ unsigned short Bs[128 * 32];
  const int tid = threadIdx.x;
  const int l = tid & 63, w = tid >> 6;
  const int lr = l & 15, lg = l >> 4;
  const int wm = w >> 1, wn = w & 1;
  const int tiles_n = N >> 7;
  const int tm = blockIdx.x / tiles_n, tn = blockIdx.x % tiles_n;
  const int bm0 = tm << 7, bn0 = tn << 7;

  f32x4 acc[4][4] = {};

  for (int kt = 0; kt < K; kt += 32) {
#pragma unroll
    for (int i = 0; i < 2; ++i) {
      int ch = tid + (i << 8);
      int row = ch >> 2, cc = ch & 3;
      const unsigned short* ga = A + (size_t)(bm0 + row) * K + kt + cc * 8;
      const unsigned short* gb = Bt + (size_t)(bn0 + row) * K + kt + cc * 8;
      unsigned short* la = As + ((size_t)((i << 8) + (w << 6))) * 8;
      unsigned short* lb = Bs + ((size_t)((i << 8) + (w << 6))) * 8;
      gload_lds16(ga, la);
      gload_lds16(gb, lb);
    }
    __syncthreads();
    short8 af[4], bf[4];
#pragma unroll
    for (int mi = 0; mi < 4; ++mi)
      af[mi] = *reinterpret_cast<const short8*>(As + (wm * 64 + mi * 16 + lr) * 32 + lg * 8);
#pragma unroll
    for (int ni = 0; ni < 4; ++ni)
      bf[ni] = *reinterpret_cast<const short8*>(Bs + (wn * 64 + ni * 16 + lr) * 32 + lg * 8);
#pragma unroll
    for (int mi = 0; mi < 4; ++mi)
#pragma unroll
      for (int ni = 0; ni < 4; ++ni)
        acc[mi][ni] = __builtin_amdgcn_mfma_f32_16x16x32_bf16(af[mi], bf[ni], acc[mi][ni], 0, 0, 0);
    __syncthreads();
  }

#pragma unroll
  for (int mi = 0; mi < 4; ++mi)
#pragma unroll
    for (int ni = 0; ni < 4; ++ni)
#pragma unroll
      for (int r = 0; r < 4; ++r) {
        int row = bm0 + wm * 64 + mi * 16 + lg * 4 + r;
        int col = bn0 + wn * 64 + ni * 16 + lr;
        float v = acc[mi][ni][r];
        if (RELU) v = fmaxf(v, 0.f);
        if constexpr (sizeof(TOUT) == 2) {
          reinterpret_cast<unsigned short*>(C)[(size_t)row * N + col] = f2bu(v);
        } else {
          C[(size_t)row * N + col] = v;
        }
      }
}

// ---------- xex scrub: invalid tags (all-zero) at coherence point, each launch ----------
__global__ void xscrub_kernel(char* xexb) {
  size_t idx = (size_t)blockIdx.x * blockDim.x + threadIdx.x;
  u32x4 z = {0, 0, 0, 0};
  store16_coh(xexb + idx * 16, z);
}

// ---------- recurrence: flag-free tag-verified exchange, late-DMA schedule ----------
// 64 blocks = 16 groups x 4 quarters. W-quarter LDS-resident. x image per
// group/parity: [4 slices][16 rows][256B], byte = q*4096 + i*256 +
// ((2*jc)^((i&7)<<4)). Tag: bit16 of dword at pair-pos p equals s^(p&1),
// s=(t>>1)&1. Producer publishes tagged slice sc0sc1 fire-and-forget.
// Consumer issues the DMA LATE (after deferred X/Y + G-prefetch + own-quarter
// MFMAs) so peers' publishes have ~2us to land -> first check almost always
// fresh; retry loop (cap 64) kept as correctness net.
__global__ __launch_bounds__(256)
void recurrence_tf(const float* __restrict__ Whh1,
                   const float* __restrict__ x0f,
                   const float* __restrict__ G,
                   char* xexb,              // [2][16 groups][16KB]
                   float* __restrict__ X, float* __restrict__ Y) {
  __shared__ char smem[163840];   // [0,128K) W; [128K,144K) xls0; [144K,160K) xls1
  const int tid = threadIdx.x;
  const int l = tid & 63, wv = tid >> 6;
  const int lr = l & 15, lg = l >> 4;
  const int bid = blockIdx.x;
  const int g = ((bid & 7) << 1) | ((bid >> 3) & 1);
  const int q = bid >> 4;
  const int r0 = g << 4;
  const int jbw = wv << 5;
  char* Wl = smem;
  char* xls0 = smem + 131072;
  char* xls1 = smem + 147456;

  // ---- one-time: swizzled W-quarter image (rows 128q..128q+128) ----
  {
    int j = tid >> 1;
    int kc0 = (tid & 1) << 8;
    const float* wr = Whh1 + (size_t)(128 * q + j) * 512 + kc0;
    int sw = (j & 7) << 4;
    for (int kk = 0; kk < 256; kk += 8) {
      float4 f0 = reinterpret_cast<const float4*>(wr + kk)[0];
      float4 f1 = reinterpret_cast<const float4*>(wr + kk)[1];
      uint4 o;
      o.x = pk2(f0.x, f0.y); o.y = pk2(f0.z, f0.w);
      o.z = pk2(f1.x, f1.y); o.w = pk2(f1.z, f1.w);
      *reinterpret_cast<uint4*>(Wl + j * 1024 + ((2 * (kc0 + kk)) ^ sw)) = o;
    }
  }
  // ---- one-time: full x_0 image into xls0 (untagged; never exchanged) ----
#pragma unroll
  for (int c = 0; c < 4; ++c) {
    int id = tid + (c << 8);
    int row = id >> 6;
    int kc = (id & 63) << 3;
    int qq = kc >> 7, kp = kc & 127;
    const float* src = x0f + (size_t)(r0 + row) * 512 + kc;
    float4 f0 = reinterpret_cast<const float4*>(src)[0];
    float4 f1 = reinterpret_cast<const float4*>(src)[1];
    uint4 o;
    o.x = pk2(f0.x, f0.y); o.y = pk2(f0.z, f0.w);
    o.z = pk2(f1.x, f1.y); o.w = pk2(f1.z, f1.w);
    *reinterpret_cast<uint4*>(xls0 + qq * 4096 + row * 256 +
                              ((2 * kp) ^ ((row & 7) << 4))) = o;
  }

  // G for t=0
  float gcur[8], gnxt[8];
#pragma unroll
  for (int jt = 0; jt < 2; ++jt)
#pragma unroll
    for (int r = 0; r < 4; ++r)
      gcur[jt * 4 + r] = G[((size_t)r0 + lg * 4 + r) * 512 + q * 128 + jbw + jt * 16 + lr];
  __syncthreads();

  const int swzR = (lr & 7) << 4;
  int rq[3];
  {
    int n = 0;
    for (int qq = 0; qq < 4; ++qq)
      if (qq != q) rq[n++] = qq;
  }
  float vsave[8];
  short8 arr[12];
  int ep = 1;   // monotone epoch for verdict word (block-uniform)

  for (int t = 0; t < 256; ++t) {
    char* xc = (t & 1) ? xls1 : xls0;
    const unsigned sh = (unsigned)(((t >> 1) & 1) << 16);
    const u32x4 e = {sh, sh ^ 0x10000u, sh, sh ^ 0x10000u};

    // ---- phase 0: deferred X/Y for t-1, G prefetch for t+1 (issue early) ----
    if (t) {
      float* Xp = X + ((size_t)(t - 1) * 256 + r0) * 512 + q * 128;
#pragma unroll
      for (int jt = 0; jt < 2; ++jt)
#pragma unroll
        for (int r = 0; r < 4; ++r)
          Xp[(size_t)(lg * 4 + r) * 512 + jbw + jt * 16 + lr] = vsave[jt * 4 + r];
      if (q == 3 && wv == 3 && lr == 15)
#pragma unroll
        for (int r = 0; r < 4; ++r)
          Y[(t - 1) * 256 + r0 + lg * 4 + r] = vsave[4 + r];
    }
    {
      int tn = (t < 255) ? t + 1 : t;
      const float* Gn = G + ((size_t)tn * 256 + r0) * 512 + q * 128;
#pragma unroll
      for (int jt = 0; jt < 2; ++jt)
#pragma unroll
        for (int r = 0; r < 4; ++r)
          gnxt[jt * 4 + r] = Gn[(size_t)(lg * 4 + r) * 512 + jbw + jt * 16 + lr];
    }

    // ---- phase A: own-quarter MFMAs (local LDS — gives producers slack) ----
    f32x4 acc[2] = {};
    {
      short8 ao[4];
#pragma unroll
      for (int kp = 0; kp < 4; ++kp)
        ao[kp] = *reinterpret_cast<const short8*>(
            xc + q * 4096 + lr * 256 + ((kp * 64 + lg * 16) ^ swzR));
#pragma unroll
      for (int jt = 0; jt < 2; ++jt) {
        int jl = jbw + jt * 16 + lr;
        const char* wb = Wl + jl * 1024;
        int swj = (jl & 7) << 4;
#pragma unroll
        for (int kp = 0; kp < 4; ++kp) {
          short8 wf = *reinterpret_cast<const short8*>(
              wb + (((q * 4 + kp) * 64 + lg * 16) ^ swj));
          acc[jt] = __builtin_amdgcn_mfma_f32_16x16x32_bf16(ao[kp], wf, acc[jt], 0, 0, 0);
        }
      }
    }

    // ---- phase B: LATE DMA of remote slices, land, tag-verify (retry net) ----
    unsigned mybad = 0;
#define READCHECK()                                                           \
  {                                                                           \
    mybad = 0;                                                                \
    _Pragma("unroll") for (int m = 0; m < 3; ++m) {                           \
      int qq = rq[m];                                                         \
      _Pragma("unroll") for (int kp = 0; kp < 4; ++kp) {                      \
        short8 f = *reinterpret_cast<const short8*>(                          \
            xc + qq * 4096 + lr * 256 + ((kp * 64 + lg * 16) ^ swzR));        \
        arr[m * 4 + kp] = f;                                                  \
        u32x4 d = __builtin_bit_cast(u32x4, f);                               \
        u32x4 xr = (d ^ e) & 0x10000u;                                        \
        mybad |= xr.x | xr.y | xr.z | xr.w;                                   \
      }                                                                       \
    }                                                                         \
  }
    if (t) {
      const char* xsb = xexb + (((t & 1) * 16 + g) * 16384);
#pragma unroll
      for (int m = 0; m < 3; ++m)
        gload_lds16_coh(xsb + rq[m] * 4096 + wv * 1024 + (size_t)l * 16,
                        xc + rq[m] * 4096 + wv * 1024);
      asm volatile("s_waitcnt vmcnt(0)" ::: "memory");
      __builtin_amdgcn_sched_barrier(0);
      __syncthreads();
      READCHECK();
      int* badw = (int*)(xc + q * 4096);   // aliases own-slice dword0 (safe: phase-A reads done)
      for (int it = 0; it < 64; ++it) {
        if (__any(mybad != 0)) { if (l == 0) *badw = ep; }
        __syncthreads();
        bool bad = (*badw == ep);
        ++ep;
        if (!bad) break;
#pragma unroll
        for (int m = 0; m < 3; ++m)
          gload_lds16_coh(xsb + rq[m] * 4096 + wv * 1024 + (size_t)l * 16,
                          xc + rq[m] * 4096 + wv * 1024);
        asm volatile("s_waitcnt vmcnt(0)" ::: "memory");
        __builtin_amdgcn_sched_barrier(0);
        __syncthreads();
        READCHECK();
      }
    } else {
      READCHECK();   // all-local x0, no verification needed
    }
#undef READCHECK

    // ---- phase C: remote-quarter MFMAs from verified frags ----
#pragma unroll
    for (int m = 0; m < 3; ++m) {
      int qq = rq[m];
#pragma unroll
      for (int jt = 0; jt < 2; ++jt) {
        int jl = jbw + jt * 16 + lr;
        const char* wb = Wl + jl * 1024;
        int swj = (jl & 7) << 4;
#pragma unroll
        for (int kp = 0; kp < 4; ++kp) {
          short8 wf = *reinterpret_cast<const short8*>(
              wb + (((qq * 4 + kp) * 64 + lg * 16) ^ swj));
          acc[jt] = __builtin_amdgcn_mfma_f32_16x16x32_bf16(arr[m * 4 + kp], wf, acc[jt], 0, 0, 0);
        }
      }
    }

    // ---- phase D: epilogue ----
#pragma unroll
    for (int jt = 0; jt < 2; ++jt)
#pragma unroll
      for (int r = 0; r < 4; ++r)
        vsave[jt * 4 + r] = fmaxf(gcur[jt * 4 + r] + acc[jt][r], 0.f);
#pragma unroll
    for (int ee = 0; ee < 8; ++ee) gcur[ee] = gnxt[ee];

    if (t < 255) {
      char* xn = (t & 1) ? xls0 : xls1;
      const unsigned snext = (unsigned)(((t + 1) >> 1) & 1);
#pragma unroll
      for (int jt = 0; jt < 2; ++jt)
#pragma unroll
        for (int r = 0; r < 4; ++r) {
          float v = vsave[jt * 4 + r];
          float vn = __shfl_xor(v, 1);
          if (!(lr & 1)) {
            int i = lg * 4 + r;
            int jc = jbw + jt * 16 + lr;
            unsigned pv = pk2(v, vn);
            pv = (pv & ~0x10000u) | ((snext ^ (unsigned)((jc >> 1) & 1)) << 16);
            *reinterpret_cast<unsigned int*>(
                xn + q * 4096 + i * 256 + ((2 * jc) ^ ((i & 7) << 4))) = pv;
          }
        }
      // publish own slice: coalesced, fire-and-forget (tag IS the flag)
      __syncthreads();
      char* xd = xexb + ((((t + 1) & 1) * 16 + g) * 16384) + q * 4096;
      u32x4 val = *reinterpret_cast<const u32x4*>(xn + q * 4096 + tid * 16);
      store16_coh(xd + tid * 16, val);
    }
  }

  // final X/Y for t=255
  {
    float* Xp = X + ((size_t)255 * 256 + r0) * 512 + q * 128;
#pragma unroll
    for (int jt = 0; jt < 2; ++jt)
#pragma unroll
      for (int r = 0; r < 4; ++r)
        Xp[(size_t)(lg * 4 + r) * 512 + jbw + jt * 16 + lr] = vsave[jt * 4 + r];
    if (q == 3 && wv == 3 && lr == 15)
#pragma unroll
      for (int r = 0; r < 4; ++r)
        Y[255 * 256 + r0 + lg * 4 + r] = vsave[4 + r];
  }
}

// ---------- launch ----------
extern "C" void kernel_launch(void* const* d_in, const int* in_sizes, int n_in,
                              void* d_out, int out_size, void* d_ws, size_t ws_size,
                              hipStream_t stream) {
  const float* x0   = (const float*)d_in[0];
  const float* Mf   = (const float*)d_in[1];
  const float* DTf  = (const float*)d_in[2];
  const float* Df   = (const float*)d_in[3];
  const float* Wih0 = (const float*)d_in[4];
  const float* Wih1 = (const float*)d_in[6];
  const float* Whh1 = (const float*)d_in[7];

  char* ws = (char*)d_ws;
  unsigned short* ins = (unsigned short*)(ws);
  unsigned short* H   = (unsigned short*)(ws + 134217728ULL);
  unsigned short* w0b = (unsigned short*)(ws + 268435456ULL);
  unsigned short* w1b = (unsigned short*)(ws + 270532608ULL);
  char* xex           = ws + 271581184ULL;                     // 512KB: [2][16][16KB]
  float* G = (float*)(ws);   // aliases ins (dead after GEMM1)

  xscrub_kernel<<<128, 256, 0, stream>>>(xex);   // invalid tags each launch (replay-safe)
  cast_concat_kernel<<<32768, 256, 0, stream>>>(Mf, DTf, Df, ins);
  cast_w_kernel<<<512, 256, 0, stream>>>(Wih0, w0b, 131072);
  cast_w_kernel<<<256, 256, 0, stream>>>(Wih1, w1b, 65536);

  gemm_bt_kernel<1, unsigned short><<<(65536 / 128) * (1024 / 128), 256, 0, stream>>>(
      ins, w0b, H, 65536, 1024, 1024);
  gemm_bt_kernel<0, float><<<(65536 / 128) * (512 / 128), 256, 0, stream>>>(
      H, w1b, G, 65536, 512, 1024);

  float* X = (float*)d_out;
  float* Y = X + 33554432;
  recurrence_tf<<<64, 256, 0, stream>>>(Whh1, x0, G, xex, X, Y);
}